// Round 2
// baseline (233.418 us; speedup 1.0000x reference)
//
#include <hip/hip_runtime.h>

#define BS   16
#define NPTS 4096
#define CH   32
#define HID  16
#define NORB 64

// One block per batch. 1024 threads = 32 points x 32 channels per iteration.
__global__ __launch_bounds__(1024) void gigp_fused(
    const float* __restrict__ coords, // [BS][N][2][2] fp32
    const float* __restrict__ vals,   // [BS][N][CH]   fp32
    const int*   __restrict__ mask,   // [BS][N]       int32 0/1
    const float* __restrict__ W1,     // [CH][HID]
    const float* __restrict__ b1,     // [HID]
    const float* __restrict__ W2,     // [HID][HID]
    const float* __restrict__ b2,     // [HID]
    const float* __restrict__ W3,     // [HID][1]
    const float* __restrict__ b3,     // [1]
    float*       __restrict__ out)    // [BS]
{
    // +1 pad: atomic phase stays 2-accesses/bank, MLP read phase conflict-free
    __shared__ float agg[NORB][CH + 1];
    __shared__ float orbout[NORB];

    const int b   = blockIdx.x;
    const int tid = threadIdx.x;

    // zero LDS accumulators
    for (int i = tid; i < NORB * (CH + 1); i += blockDim.x)
        (&agg[0][0])[i] = 0.0f;
    __syncthreads();

    const int c     = tid & 31;   // channel
    const int pbase = tid >> 5;   // 0..31 point-within-iteration

    for (int it = 0; it < NPTS / 32; ++it) {
        const int n  = it * 32 + pbase;
        const int gi = b * NPTS + n;
        // orbit id lives at coords[b][n][1][1] = flat gi*4 + 3
        const int   k = (int)coords[(size_t)gi * 4 + 3];
        const int   m = mask[gi];
        const float v = vals[(size_t)gi * CH + c];
        if (m) {
            atomicAdd(&agg[k][c], v);          // ds_add_f32
        }
    }
    __syncthreads();

    // MLP per orbit: one thread per orbit (wave 0 only)
    if (tid < NORB) {
        const int k = tid;

        // empty-orbit test exactly as reference: sum over channels == 0
        float chsum = 0.0f;
        #pragma unroll
        for (int cc = 0; cc < CH; ++cc) chsum += agg[k][cc];

        float h1[HID];
        #pragma unroll
        for (int j = 0; j < HID; ++j) h1[j] = b1[j];
        for (int cc = 0; cc < CH; ++cc) {
            const float a = agg[k][cc];
            #pragma unroll
            for (int j = 0; j < HID; ++j)
                h1[j] += a * W1[cc * HID + j];
        }
        #pragma unroll
        for (int j = 0; j < HID; ++j) h1[j] = h1[j] > 0.0f ? h1[j] : 0.0f;

        float h2[HID];
        #pragma unroll
        for (int j = 0; j < HID; ++j) h2[j] = b2[j];
        for (int i = 0; i < HID; ++i) {
            const float a = h1[i];
            #pragma unroll
            for (int j = 0; j < HID; ++j)
                h2[j] += a * W2[i * HID + j];
        }
        float o = b3[0];
        #pragma unroll
        for (int i = 0; i < HID; ++i) {
            const float a = h2[i] > 0.0f ? h2[i] : 0.0f;
            o += a * W3[i];
        }
        orbout[k] = (chsum == 0.0f) ? 0.0f : o;
    }
    __syncthreads();

    if (tid == 0) {
        float s = 0.0f;
        for (int k = 0; k < NORB; ++k) s += orbout[k];
        out[b] = s;
    }
}

extern "C" void kernel_launch(void* const* d_in, const int* in_sizes, int n_in,
                              void* d_out, int out_size, void* d_ws, size_t ws_size,
                              hipStream_t stream) {
    const float* coords = (const float*)d_in[0];
    const float* vals   = (const float*)d_in[1];
    const int*   mask   = (const int*)d_in[2];
    const float* W1     = (const float*)d_in[3];
    const float* b1     = (const float*)d_in[4];
    const float* W2     = (const float*)d_in[5];
    const float* b2     = (const float*)d_in[6];
    const float* W3     = (const float*)d_in[7];
    const float* b3     = (const float*)d_in[8];
    // d_in[9] = n_orbs (scalar int, known 64) — intentionally unused
    float* out = (float*)d_out;

    gigp_fused<<<BS, 1024, 0, stream>>>(coords, vals, mask,
                                        W1, b1, W2, b2, W3, b3, out);
}

// Round 3
// 97.472 us; speedup vs baseline: 2.3947x; 2.3947x over previous
//
#include <hip/hip_runtime.h>

#define BS     16
#define NPTS   4096
#define CH     32
#define HID    16
#define NORB   64
#define SLICES 32
#define PPB    (NPTS / SLICES)   // 128 points per block

// Stage A: per-slice LDS aggregation, then global atomic push into ws[BS][NORB][CH].
// grid = BS*SLICES blocks x 256 threads. Lane mapping per iteration:
//   pl = tid>>3 (32 points), c4 = tid&7 (8 float4 channel groups) -> 1 KB coalesced/wave.
__global__ __launch_bounds__(256) void gigp_agg(
    const float* __restrict__ coords, // [BS][N][2][2]
    const float* __restrict__ vals,   // [BS][N][CH]
    const int*   __restrict__ mask,   // [BS][N]
    float*       __restrict__ ws)     // [BS][NORB][CH] (pre-zeroed)
{
    // +1 pad: random-k atomic phase spreads banks; read-out phase 2 lanes/bank (free)
    __shared__ float agg[NORB][CH + 1];

    const int tid   = threadIdx.x;
    const int b     = blockIdx.x >> 5;    // / SLICES
    const int slice = blockIdx.x & (SLICES - 1);

    for (int i = tid; i < NORB * (CH + 1); i += 256)
        (&agg[0][0])[i] = 0.0f;
    __syncthreads();

    const int c4 = tid & 7;
    const int pl = tid >> 3;
    const float4* vals4 = (const float4*)vals;

    #pragma unroll
    for (int it = 0; it < PPB / 32; ++it) {      // 4 iterations
        const int n  = slice * PPB + it * 32 + pl;
        const int gi = b * NPTS + n;
        const int   k = (int)coords[(size_t)gi * 4 + 3]; // coords[b][n][1][1]
        const int   m = mask[gi];
        const float4 v = vals4[(size_t)gi * 8 + c4];
        if (m) {
            atomicAdd(&agg[k][c4 * 4 + 0], v.x);
            atomicAdd(&agg[k][c4 * 4 + 1], v.y);
            atomicAdd(&agg[k][c4 * 4 + 2], v.z);
            atomicAdd(&agg[k][c4 * 4 + 3], v.w);
        }
    }
    __syncthreads();

    // push nonzero partials to the global accumulator
    for (int e = tid; e < NORB * CH; e += 256) {
        const int k = e >> 5;
        const int c = e & 31;
        const float v = agg[k][c];
        if (v != 0.0f)
            atomicAdd(&ws[((size_t)b * NORB + k) * CH + c], v);
    }
}

// Stage B: one block per batch, one thread per orbit (64 = exactly one wave).
__global__ __launch_bounds__(64) void gigp_mlp(
    const float* __restrict__ ws,  // [BS][NORB][CH]
    const float* __restrict__ W1, const float* __restrict__ b1,
    const float* __restrict__ W2, const float* __restrict__ b2,
    const float* __restrict__ W3, const float* __restrict__ b3,
    float*       __restrict__ out) // [BS]
{
    const int b = blockIdx.x;
    const int k = threadIdx.x;

    float a[CH];
    const float4* w4 = (const float4*)(ws + ((size_t)b * NORB + k) * CH);
    float chsum = 0.0f;
    #pragma unroll
    for (int i = 0; i < CH / 4; ++i) {
        const float4 t = w4[i];
        a[i * 4 + 0] = t.x; a[i * 4 + 1] = t.y;
        a[i * 4 + 2] = t.z; a[i * 4 + 3] = t.w;
        chsum += t.x + t.y + t.z + t.w;
    }

    float h1[HID];
    #pragma unroll
    for (int j = 0; j < HID; ++j) h1[j] = b1[j];
    #pragma unroll
    for (int cc = 0; cc < CH; ++cc) {
        const float x = a[cc];
        #pragma unroll
        for (int j = 0; j < HID; ++j)
            h1[j] += x * W1[cc * HID + j];
    }
    #pragma unroll
    for (int j = 0; j < HID; ++j) h1[j] = h1[j] > 0.0f ? h1[j] : 0.0f;

    float h2[HID];
    #pragma unroll
    for (int j = 0; j < HID; ++j) h2[j] = b2[j];
    #pragma unroll
    for (int i = 0; i < HID; ++i) {
        const float x = h1[i];
        #pragma unroll
        for (int j = 0; j < HID; ++j)
            h2[j] += x * W2[i * HID + j];
    }
    float o = b3[0];
    #pragma unroll
    for (int i = 0; i < HID; ++i) {
        const float x = h2[i] > 0.0f ? h2[i] : 0.0f;
        o += x * W3[i];
    }
    o = (chsum == 0.0f) ? 0.0f : o;

    // wave reduction over the 64 orbits (one wave)
    #pragma unroll
    for (int off = 32; off > 0; off >>= 1)
        o += __shfl_down(o, off);
    if (k == 0) out[b] = o;
}

extern "C" void kernel_launch(void* const* d_in, const int* in_sizes, int n_in,
                              void* d_out, int out_size, void* d_ws, size_t ws_size,
                              hipStream_t stream) {
    const float* coords = (const float*)d_in[0];
    const float* vals   = (const float*)d_in[1];
    const int*   mask   = (const int*)d_in[2];
    const float* W1     = (const float*)d_in[3];
    const float* b1     = (const float*)d_in[4];
    const float* W2     = (const float*)d_in[5];
    const float* b2     = (const float*)d_in[6];
    const float* W3     = (const float*)d_in[7];
    const float* b3     = (const float*)d_in[8];
    float* out = (float*)d_out;
    float* ws  = (float*)d_ws;

    // ws is poisoned 0xAA before every launch — zero the accumulator region
    hipMemsetAsync(ws, 0, (size_t)BS * NORB * CH * sizeof(float), stream);

    gigp_agg<<<BS * SLICES, 256, 0, stream>>>(coords, vals, mask, ws);
    gigp_mlp<<<BS, 64, 0, stream>>>(ws, W1, b1, W2, b2, W3, b3, out);
}

// Round 4
// 97.437 us; speedup vs baseline: 2.3956x; 1.0004x over previous
//
#include <hip/hip_runtime.h>

#define BS     16
#define NPTS   4096
#define CH     32
#define HID    16
#define NORB   64
#define SLICES 32
#define PPB    (NPTS / SLICES)   // 128 points per block
#define ITERS  (PPB / 32)        // 4

// Stage A: per-slice LDS aggregation, deterministic float4 store of partials.
// grid = BS*SLICES blocks x 256 threads. part layout: [BS][SLICES][NORB][CH].
__global__ __launch_bounds__(256) void gigp_agg(
    const float* __restrict__ coords, // [BS][N][2][2]
    const float* __restrict__ vals,   // [BS][N][CH]
    const int*   __restrict__ mask,   // [BS][N]
    float*       __restrict__ part)   // [BS][SLICES][NORB][CH]
{
    // +1 pad: atomic phase spreads banks by (k+c)%32
    __shared__ float agg[NORB][CH + 1];

    const int tid   = threadIdx.x;
    const int b     = blockIdx.x >> 5;          // / SLICES
    const int slice = blockIdx.x & (SLICES - 1);

    for (int i = tid; i < NORB * (CH + 1); i += 256)
        (&agg[0][0])[i] = 0.0f;

    const int c4 = tid & 7;
    const int pl = tid >> 3;
    const float4* vals4 = (const float4*)vals;

    // prefetch all iterations (independent loads in flight)
    int    kk[ITERS];
    int    mm[ITERS];
    float4 vv[ITERS];
    #pragma unroll
    for (int it = 0; it < ITERS; ++it) {
        const int n  = slice * PPB + it * 32 + pl;
        const int gi = b * NPTS + n;
        kk[it] = (int)coords[(size_t)gi * 4 + 3]; // coords[b][n][1][1]
        mm[it] = mask[gi];
        vv[it] = vals4[(size_t)gi * 8 + c4];
    }
    __syncthreads();   // LDS zeroing done

    #pragma unroll
    for (int it = 0; it < ITERS; ++it) {
        if (mm[it]) {
            const int k = kk[it];
            atomicAdd(&agg[k][c4 * 4 + 0], vv[it].x);
            atomicAdd(&agg[k][c4 * 4 + 1], vv[it].y);
            atomicAdd(&agg[k][c4 * 4 + 2], vv[it].z);
            atomicAdd(&agg[k][c4 * 4 + 3], vv[it].w);
        }
    }
    __syncthreads();

    // deterministic partial store: 512 float4 per block, coalesced
    float4* dst = (float4*)(part + ((size_t)b * SLICES + slice) * NORB * CH);
    #pragma unroll
    for (int j = 0; j < 2; ++j) {
        const int e  = tid + j * 256;   // float4 index within [NORB][CH/4]
        const int k  = e >> 3;
        const int c4v = e & 7;
        float4 t;
        t.x = agg[k][c4v * 4 + 0];
        t.y = agg[k][c4v * 4 + 1];
        t.z = agg[k][c4v * 4 + 2];
        t.w = agg[k][c4v * 4 + 3];
        dst[e] = t;
    }
}

// Stage B: reduce 32 slices + MLP. grid = BS blocks x 256 threads.
__global__ __launch_bounds__(256) void gigp_mlp(
    const float* __restrict__ part, // [BS][SLICES][NORB][CH]
    const float* __restrict__ W1, const float* __restrict__ b1,
    const float* __restrict__ W2, const float* __restrict__ b2,
    const float* __restrict__ W3, const float* __restrict__ b3,
    float*       __restrict__ out)  // [BS]
{
    __shared__ float agg[NORB][CH + 1];   // pad: MLP phase reads bank (k+c)%32

    const int b   = blockIdx.x;
    const int tid = threadIdx.x;

    const float4* src = (const float4*)(part + (size_t)b * SLICES * NORB * CH);

    float4 a0 = make_float4(0.f, 0.f, 0.f, 0.f);
    float4 a1 = make_float4(0.f, 0.f, 0.f, 0.f);
    #pragma unroll
    for (int s = 0; s < SLICES; ++s) {
        const float4 t0 = src[(size_t)s * (NORB * CH / 4) + tid];
        const float4 t1 = src[(size_t)s * (NORB * CH / 4) + tid + 256];
        a0.x += t0.x; a0.y += t0.y; a0.z += t0.z; a0.w += t0.w;
        a1.x += t1.x; a1.y += t1.y; a1.z += t1.z; a1.w += t1.w;
    }
    {
        const int e0 = tid, e1 = tid + 256;
        const int k0 = e0 >> 3, c0 = (e0 & 7) * 4;
        const int k1 = e1 >> 3, c1 = (e1 & 7) * 4;
        agg[k0][c0 + 0] = a0.x; agg[k0][c0 + 1] = a0.y;
        agg[k0][c0 + 2] = a0.z; agg[k0][c0 + 3] = a0.w;
        agg[k1][c1 + 0] = a1.x; agg[k1][c1 + 1] = a1.y;
        agg[k1][c1 + 2] = a1.z; agg[k1][c1 + 3] = a1.w;
    }
    __syncthreads();

    if (tid < NORB) {
        const int k = tid;

        float chsum = 0.0f;
        #pragma unroll
        for (int cc = 0; cc < CH; ++cc) chsum += agg[k][cc];

        float h1[HID];
        #pragma unroll
        for (int j = 0; j < HID; ++j) h1[j] = b1[j];
        #pragma unroll
        for (int cc = 0; cc < CH; ++cc) {
            const float x = agg[k][cc];
            #pragma unroll
            for (int j = 0; j < HID; ++j)
                h1[j] += x * W1[cc * HID + j];
        }
        #pragma unroll
        for (int j = 0; j < HID; ++j) h1[j] = h1[j] > 0.0f ? h1[j] : 0.0f;

        float h2[HID];
        #pragma unroll
        for (int j = 0; j < HID; ++j) h2[j] = b2[j];
        #pragma unroll
        for (int i = 0; i < HID; ++i) {
            const float x = h1[i];
            #pragma unroll
            for (int j = 0; j < HID; ++j)
                h2[j] += x * W2[i * HID + j];
        }
        float o = b3[0];
        #pragma unroll
        for (int i = 0; i < HID; ++i) {
            const float x = h2[i] > 0.0f ? h2[i] : 0.0f;
            o += x * W3[i];
        }
        o = (chsum == 0.0f) ? 0.0f : o;

        // one-wave reduction over 64 orbits
        #pragma unroll
        for (int off = 32; off > 0; off >>= 1)
            o += __shfl_down(o, off);
        if (k == 0) out[b] = o;
    }
}

extern "C" void kernel_launch(void* const* d_in, const int* in_sizes, int n_in,
                              void* d_out, int out_size, void* d_ws, size_t ws_size,
                              hipStream_t stream) {
    const float* coords = (const float*)d_in[0];
    const float* vals   = (const float*)d_in[1];
    const int*   mask   = (const int*)d_in[2];
    const float* W1     = (const float*)d_in[3];
    const float* b1     = (const float*)d_in[4];
    const float* W2     = (const float*)d_in[5];
    const float* b2     = (const float*)d_in[6];
    const float* W3     = (const float*)d_in[7];
    const float* b3     = (const float*)d_in[8];
    float* out  = (float*)d_out;
    float* part = (float*)d_ws;   // 16*32*64*32*4 = 4 MB, fully written by stage A

    gigp_agg<<<BS * SLICES, 256, 0, stream>>>(coords, vals, mask, part);
    gigp_mlp<<<BS, 256, 0, stream>>>(part, W1, b1, W2, b2, W3, b3, out);
}